// Round 4
// baseline (271.217 us; speedup 1.0000x reference)
//
#include <hip/hip_runtime.h>

// Problem constants: B=16, R=1, A=16, T=14, S=1024
static constexpr int kB = 16;
static constexpr int kA = 16;
static constexpr int kT = 14;
static constexpr int kS = 1024;
static constexpr int kMaxMatch = 32;

// y layout: (B, R=1, A, T, S) float32 contiguous.
// Output: (B, R=1, T, S, A, A) float32 = real(cov), flat (confirmed R3, absmax 0).

// --------------------------------------------------------------------------
// Kernel 1: per subcarrier s, compute nearest-neighbor covariance for all b:
//   ws[b, s, i, j] = mean_m( xr_i xr_j + xi_i xi_j ) at c = closest[s]
// grid = S blocks, 256 threads; thread owns (i = tid>>4, j = tid&15).
// --------------------------------------------------------------------------
__global__ __launch_bounds__(256) void cov_nn_kernel(
    const float* __restrict__ y_real,
    const float* __restrict__ y_imag,
    const int*   __restrict__ est,      // (P,2): [sym, sc] int32 (sniffs int64)
    const int*   __restrict__ closest,  // (S,)  int32 (sniffs int64)
    float*       __restrict__ ws,       // B*S*A*A floats
    int P)
{
    const int s   = blockIdx.x;
    const int tid = threadIdx.x;

    // layout sniff: int64 arrays of small values have all-zero odd words
    bool est64 = true;
    {
        int lim = 2 * P; if (lim > 128) lim = 128;
        for (int k = 1; k < lim; k += 2)
            if (est[k] != 0) { est64 = false; break; }
    }
    bool clo64 = true;
    {
        int lim = kS; if (lim > 128) lim = 128;
        for (int k = 1; k < lim; k += 2)
            if (closest[k] != 0) { clo64 = false; break; }
    }

    int c = closest[clo64 ? 2 * s : s];
    if (c < 0) c = 0;
    if (c >= kS) c = kS - 1;

    __shared__ int sm_count;
    __shared__ int sm_sym[kMaxMatch];

    if (tid == 0) sm_count = 0;
    __syncthreads();

    for (int p = tid; p < P; p += 256) {
        const int sc = est[est64 ? 4 * p + 2 : 2 * p + 1];
        if (sc == c) {
            const int sym = est[est64 ? 4 * p : 2 * p];
            if (sym >= 0 && sym < kT) {
                int slot = atomicAdd(&sm_count, 1);
                if (slot < kMaxMatch) sm_sym[slot] = sym;
            }
        }
    }
    __syncthreads();

    int count = sm_count;
    if (count > kMaxMatch) count = kMaxMatch;
    const float inv = 1.0f / (float)(count > 0 ? count : 1);

    const int i = tid >> 4;
    const int j = tid & 15;

    __shared__ float sre[16][kA], sim[16][kA];

    for (int b = 0; b < kB; ++b) {
        float sum = 0.f;
        for (int m0 = 0; m0 < count; m0 += 16) {
            int mm = count - m0; if (mm > 16) mm = 16;
            const int mload = tid >> 4;      // 0..15
            const int aload = tid & 15;
            if (mload < mm) {
                const int sym = sm_sym[m0 + mload];
                const long off = (long)b * (kA * kT * kS)
                               + (long)aload * (kT * kS)
                               + (long)sym * kS + c;
                sre[mload][aload] = y_real[off];
                sim[mload][aload] = y_imag[off];
            }
            __syncthreads();
            for (int m = 0; m < mm; ++m)
                sum += sre[m][i] * sre[m][j] + sim[m][i] * sim[m][j];
            __syncthreads();
        }
        ws[((long)b * kS + s) * 256 + tid] = sum * inv;
    }
}

// --------------------------------------------------------------------------
// Kernel 2: pure broadcast. out[b,t,s,:,:] = ws[b,s,:,:] as float4 stream.
// idx layout: (bt << 16) | (s << 6) | slot ; src = (b << 16) | (idx & 0xFFFF)
// --------------------------------------------------------------------------
__global__ __launch_bounds__(256) void bcast_kernel(
    const float4* __restrict__ ws4,
    float4*       __restrict__ out4,
    long n4)
{
    long idx = (long)blockIdx.x * blockDim.x + threadIdx.x;
    const long stride = (long)gridDim.x * blockDim.x;
    for (; idx < n4; idx += stride) {
        const int bt = (int)(idx >> 16);
        const int b  = bt / kT;                 // magic-mul, no t needed
        const long src = ((long)b << 16) | (idx & 0xFFFF);
        out4[idx] = ws4[src];
    }
}

// --------------------------------------------------------------------------
// Fallback: R3's passing monolithic kernel (used only if ws too small)
// --------------------------------------------------------------------------
__global__ __launch_bounds__(64) void cov_real_mono_kernel(
    const float* __restrict__ y_real,
    const float* __restrict__ y_imag,
    const int*   __restrict__ est,
    const int*   __restrict__ closest,
    float*       __restrict__ out,
    int P, long out_floats)
{
    const int blk = blockIdx.x;
    const int b   = blk >> 10;
    const int s   = blk & (kS - 1);
    const int tid = threadIdx.x;

    bool est64 = true;
    {
        int lim = 2 * P; if (lim > 128) lim = 128;
        for (int k = 1; k < lim; k += 2)
            if (est[k] != 0) { est64 = false; break; }
    }
    bool clo64 = true;
    {
        int lim = kS; if (lim > 128) lim = 128;
        for (int k = 1; k < lim; k += 2)
            if (closest[k] != 0) { clo64 = false; break; }
    }

    int c = closest[clo64 ? 2 * s : s];
    if (c < 0) c = 0;
    if (c >= kS) c = kS - 1;

    __shared__ int   sm_count;
    __shared__ int   sm_sym[kMaxMatch];
    __shared__ float sm_re[kA], sm_im[kA];

    if (tid == 0) sm_count = 0;
    __syncthreads();

    for (int p = tid; p < P; p += 64) {
        const int sc = est[est64 ? 4 * p + 2 : 2 * p + 1];
        if (sc == c) {
            const int sym = est[est64 ? 4 * p : 2 * p];
            if (sym >= 0 && sym < kT) {
                int slot = atomicAdd(&sm_count, 1);
                if (slot < kMaxMatch) sm_sym[slot] = sym;
            }
        }
    }
    __syncthreads();

    int count = sm_count;
    if (count > kMaxMatch) count = kMaxMatch;

    const int i  = tid >> 2;
    const int j0 = (tid & 3) * 4;

    float v0 = 0.f, v1 = 0.f, v2 = 0.f, v3 = 0.f;

    for (int m = 0; m < count; ++m) {
        const int sym = sm_sym[m];
        if (tid < kA) {
            const long off = (long)b * (kA * kT * kS) + (long)tid * (kT * kS)
                           + (long)sym * kS + c;
            sm_re[tid] = y_real[off];
            sm_im[tid] = y_imag[off];
        }
        __syncthreads();

        const float xr = sm_re[i], xi = sm_im[i];
        v0 += xr * sm_re[j0 + 0] + xi * sm_im[j0 + 0];
        v1 += xr * sm_re[j0 + 1] + xi * sm_im[j0 + 1];
        v2 += xr * sm_re[j0 + 2] + xi * sm_im[j0 + 2];
        v3 += xr * sm_re[j0 + 3] + xi * sm_im[j0 + 3];
        __syncthreads();
    }

    const float inv = 1.0f / (float)(count > 0 ? count : 1);
    const float4 v = make_float4(v0 * inv, v1 * inv, v2 * inv, v3 * inv);

    float4* __restrict__ out4 = (float4*)out;
    for (int t = 0; t < kT; ++t) {
        const long f4idx = ((long)(b * kT + t) * kS + s) * 64 + tid;
        if ((f4idx + 1) * 4 <= out_floats)
            out4[f4idx] = v;
    }
}

extern "C" void kernel_launch(void* const* d_in, const int* in_sizes, int n_in,
                              void* d_out, int out_size, void* d_ws, size_t ws_size,
                              hipStream_t stream) {
    const float* y_real  = (const float*)d_in[0];
    const float* y_imag  = (const float*)d_in[1];
    const int*   est     = (const int*)d_in[2];
    const int*   closest = (const int*)d_in[3];
    float*       out     = (float*)d_out;

    const int    P        = in_sizes[2] / 2;
    const size_t ws_need  = (size_t)kB * kS * kA * kA * sizeof(float);  // 16.7 MB

    if (ws_size >= ws_need) {
        float* cov_ws = (float*)d_ws;
        cov_nn_kernel<<<dim3(kS), dim3(256), 0, stream>>>(
            y_real, y_imag, est, closest, cov_ws, P);

        const long n4 = (long)out_size >> 2;   // float4 count
        bcast_kernel<<<dim3(8192), dim3(256), 0, stream>>>(
            (const float4*)cov_ws, (float4*)out, n4);
    } else {
        cov_real_mono_kernel<<<dim3(kB * kS), dim3(64), 0, stream>>>(
            y_real, y_imag, est, closest, out, P, (long)out_size);
    }
}